// Round 9
// baseline (701.637 us; speedup 1.0000x reference)
//
#include <hip/hip_runtime.h>
#include <cstdint>

// Problem constants (B,S,D,H) from the reference
#define B_ 64
#define S_ 2048
#define D_ 512
#define H_ 512

using f32x4  = __attribute__((ext_vector_type(4))) float;
using bf16x8 = __attribute__((ext_vector_type(8))) short;
using u32x2  = __attribute__((ext_vector_type(2))) unsigned int;

__device__ __forceinline__ unsigned short f2bf(float f) {
  unsigned u = __float_as_uint(f);
  u += 0x7FFFu + ((u >> 16) & 1u);   // round-to-nearest-even
  return (unsigned short)(u >> 16);
}
// packed f32x2 -> bf16x2 (RTE), hardware op
__device__ __forceinline__ unsigned int cvtpk(float lo, float hi) {
  unsigned int r;
  asm("v_cvt_pk_bf16_f32 %0, %1, %2" : "=v"(r) : "v"(lo), "v"(hi));
  return r;
}
// tanh via v_exp_f32: 1 - 2/(exp2(2x*log2e)+1); exact saturation at +-inf
__device__ __forceinline__ float fast_tanh(float x) {
  float t = __builtin_amdgcn_exp2f(x * 2.8853900817779268f);
  return 1.0f - 2.0f * __builtin_amdgcn_rcpf(t + 1.0f);
}

__device__ __forceinline__ void barrier_raw() {
  asm volatile("" ::: "memory");
  __builtin_amdgcn_s_barrier();
  asm volatile("" ::: "memory");
}

// ---------------------------------------------------------------------------
// k_prep: blocks [0,128): di[b,h] = hidden[b,:].Wd[h,:] + bd[h]
//         blocks [128,256): We fp32 -> bf16 (32768 chunks of 8)
__global__ void k_prep(const float* __restrict__ hidden, const float* __restrict__ Wd,
                       const float* __restrict__ bd, float* __restrict__ di,
                       const float* __restrict__ We, unsigned short* __restrict__ Web) {
  if (blockIdx.x < 128) {
    int idx = blockIdx.x * 256 + threadIdx.x;   // 32768 total
    int h = idx >> 6;
    int b = idx & 63;
    const f32x4* hp = (const f32x4*)(hidden + (size_t)b * D_);
    const f32x4* wp = (const f32x4*)(Wd + (size_t)h * D_);
    float acc = 0.f;
#pragma unroll 8
    for (int i = 0; i < D_ / 4; ++i) {
      f32x4 x = hp[i], y = wp[i];
      acc += x[0] * y[0] + x[1] * y[1] + x[2] * y[2] + x[3] * y[3];
    }
    di[b * H_ + h] = acc + bd[h];
  } else {
    int i = (blockIdx.x - 128) * 256 + threadIdx.x;   // 32768 chunks
    const f32x4* p = (const f32x4*)(We + (size_t)i * 8);
    f32x4 a = p[0], b = p[1];
    bf16x8 o;
    o[0] = (short)f2bf(a[0]); o[1] = (short)f2bf(a[1]);
    o[2] = (short)f2bf(a[2]); o[3] = (short)f2bf(a[3]);
    o[4] = (short)f2bf(b[0]); o[5] = (short)f2bf(b[1]);
    o[6] = (short)f2bf(b[2]); o[7] = (short)f2bf(b[3]);
    *(bf16x8*)(Web + (size_t)i * 8) = o;
  }
}

// ---------------------------------------------------------------------------
// ei-GEMM, fp32 A read directly; reg-staged A with in-register cvt_pk, fused
// ui partials. Tile 128x128, 4 waves (2x2), BK=32, 16 k-steps, 33KB LDS.
// THREE named register sets (a/b/c): tile T lives in set T%3. At iter kt:
//   lgkmcnt(0); barrier                  // buf[kt&1] visible block-wide
//   ds_read frags(buf[kt&1])
//   LOADN(set[kt%3], kt+3)               // 2-kstep slack to its WRITEN
//   setprio(1); 16 MFMA; setprio(0)
//   WRITEN(set[(kt+1)%3], buf^1)         // tile kt+1, loaded 2 ksteps ago
// Rationale (R8 ablation): structure-without-globals = 60us; globals added
// +100us because the TA/VMEM phase serialized with the LDS/MFMA phase at
// 1-kstep slack. 2-kstep slack lets the TA work on tiles kt+2/kt+3 while
// LDS+MFMA chew kt -> wall = max(pipes), not sum.
__global__ __launch_bounds__(256, 4) void k_ei_gemm(
    const float* __restrict__ A, const unsigned short* __restrict__ Bw,
    const float* __restrict__ be, const float* __restrict__ V,
    const float* __restrict__ di, float* __restrict__ ui4) {
  __shared__ __align__(16) unsigned short ldsA[2][128 * 32];   // 8KB each
  __shared__ __align__(16) unsigned short ldsB[2][128 * 32];
  __shared__ float ured[4][64];

  const int bid = blockIdx.x;
  const int swz = (bid & 7) * 512 + (bid >> 3);   // bijective XCD chunking (4096%8==0)
  const int row0 = (swz >> 2) << 7;               // 1024 m-tiles of 128 rows
  const int nt   = swz & 3;
  const int col0 = nt << 7;

  const int t  = threadIdx.x;
  const int l  = t & 63;
  const int w  = t >> 6;          // 4 waves, 2M x 2N
  const int wm = (w >> 1) << 6;
  const int wn = (w & 1) << 6;
  const int lr = l & 15;
  const int lg = l >> 4;

  // staging maps (A fp32 rows of 128B; B bf16 rows of 64B)
  const float* gA = A + (size_t)(row0 + w * 32 + (l >> 3)) * D_ + ((l & 7) << 2);
  const unsigned short* gB = Bw + (size_t)(col0 + w * 32 + (l >> 2)) * D_ + ((l & 3) << 3);

  // LDS write slots (16B granules, phys = logical ^ ((row>>1)&3))
  const int sA = (((l & 7) >> 1) ^ ((l >> 4) & 3));
  const int eA0 = (w * 32 + (l >> 3)) * 32 + sA * 8 + (l & 1) * 4;
  const int sB = ((l & 3) ^ ((l >> 3) & 3));
  const int eB0 = (w * 32 + (l >> 2)) * 32 + sB * 8;
  const int rs = (lg ^ ((lr >> 1) & 3)) << 3;

  // three named staging register sets (rule #20: never runtime-index)
  f32x4  rA0a, rA1a, rA2a, rA3a;  bf16x8 rB0a, rB1a;
  f32x4  rA0b, rA1b, rA2b, rA3b;  bf16x8 rB0b, rB1b;
  f32x4  rA0c, rA1c, rA2c, rA3c;  bf16x8 rB0c, rB1c;

#define LOADN(S, kk) do {                               \
    const float* a_ = gA + ((kk) << 5);                 \
    rA0##S = *(const f32x4*)(a_);                       \
    rA1##S = *(const f32x4*)(a_ + 8 * D_);              \
    rA2##S = *(const f32x4*)(a_ + 16 * D_);             \
    rA3##S = *(const f32x4*)(a_ + 24 * D_);             \
    const unsigned short* b_ = gB + ((kk) << 5);        \
    rB0##S = *(const bf16x8*)(b_);                      \
    rB1##S = *(const bf16x8*)(b_ + 16 * D_);            \
  } while (0)

#define WRITEN(S, bf) do {                                                  \
    u32x2 p0 = {cvtpk(rA0##S[0], rA0##S[1]), cvtpk(rA0##S[2], rA0##S[3])};  \
    u32x2 p1 = {cvtpk(rA1##S[0], rA1##S[1]), cvtpk(rA1##S[2], rA1##S[3])};  \
    u32x2 p2 = {cvtpk(rA2##S[0], rA2##S[1]), cvtpk(rA2##S[2], rA2##S[3])};  \
    u32x2 p3 = {cvtpk(rA3##S[0], rA3##S[1]), cvtpk(rA3##S[2], rA3##S[3])};  \
    *(u32x2*)&ldsA[bf][eA0]       = p0;                                     \
    *(u32x2*)&ldsA[bf][eA0 + 256] = p1;                                     \
    *(u32x2*)&ldsA[bf][eA0 + 512] = p2;                                     \
    *(u32x2*)&ldsA[bf][eA0 + 768] = p3;                                     \
    *(bf16x8*)&ldsB[bf][eB0]       = rB0##S;                                \
    *(bf16x8*)&ldsB[bf][eB0 + 512] = rB1##S;                                \
  } while (0)

  f32x4 acc[4][4];
  const f32x4 z = {0.f, 0.f, 0.f, 0.f};
#pragma unroll
  for (int mi = 0; mi < 4; ++mi)
#pragma unroll
    for (int ni = 0; ni < 4; ++ni) acc[mi][ni] = z;

#define KBODY(bf, LD, WR) do {                                              \
    asm volatile("s_waitcnt lgkmcnt(0)" ::: "memory");                      \
    barrier_raw();                                                          \
    bf16x8 af[4], bq[4];                                                    \
    _Pragma("unroll") for (int mi = 0; mi < 4; ++mi)                        \
      af[mi] = *(const bf16x8*)&ldsA[bf][(wm + mi * 16 + lr) * 32 + rs];    \
    _Pragma("unroll") for (int ni = 0; ni < 4; ++ni)                        \
      bq[ni] = *(const bf16x8*)&ldsB[bf][(wn + ni * 16 + lr) * 32 + rs];    \
    LD;                                                                     \
    __builtin_amdgcn_s_setprio(1);                                          \
    _Pragma("unroll") for (int mi = 0; mi < 4; ++mi)                        \
      _Pragma("unroll") for (int ni = 0; ni < 4; ++ni)                      \
        acc[mi][ni] = __builtin_amdgcn_mfma_f32_16x16x32_bf16(              \
            af[mi], bq[ni], acc[mi][ni], 0, 0, 0);                          \
    __builtin_amdgcn_s_setprio(0);                                          \
    WR;                                                                     \
  } while (0)

  // prologue: tiles 0,1,2 -> sets a,b,c; tile0 -> buf0
  LOADN(a, 0);
  LOADN(b, 1);
  LOADN(c, 2);
  WRITEN(a, 0);

  // steady state: period-6 pattern (buf mod 2, set mod 3), kt = 0..11
  for (int u = 0; u < 2; ++u) {
    const int kt = 6 * u;
    KBODY(0, LOADN(a, kt + 3), WRITEN(b, 1));   // kt+0
    KBODY(1, LOADN(b, kt + 4), WRITEN(c, 0));   // kt+1
    KBODY(0, LOADN(c, kt + 5), WRITEN(a, 1));   // kt+2
    KBODY(1, LOADN(a, kt + 6), WRITEN(b, 0));   // kt+3
    KBODY(0, LOADN(b, kt + 7), WRITEN(c, 1));   // kt+4
    KBODY(1, LOADN(c, kt + 8), WRITEN(a, 0));   // kt+5
  }
  // tail: kt = 12..15 (tile15 loaded at kt=12; no loads after)
  KBODY(0, LOADN(a, 15), WRITEN(b, 1));         // kt=12: write tile13
  KBODY(1, (void)0,      WRITEN(c, 0));         // kt=13: write tile14
  KBODY(0, (void)0,      WRITEN(a, 1));         // kt=14: write tile15
  KBODY(1, (void)0,      (void)0);              // kt=15
#undef KBODY
#undef LOADN
#undef WRITEN

  // fused ui partials over this block's 128 columns; atomic-free.
  // C/D layout: col = lr, row = lg*4 + j within each 16x16 frag.
  const int b = row0 >> 11;   // BM=128 divides S=2048 -> block-uniform batch
  float uacc[4][4];
#pragma unroll
  for (int mi = 0; mi < 4; ++mi)
#pragma unroll
    for (int j = 0; j < 4; ++j) uacc[mi][j] = 0.f;

#pragma unroll
  for (int ni = 0; ni < 4; ++ni) {
    const int gc = col0 + wn + ni * 16 + lr;
    const float vv = V[gc];
    const float base = di[b * H_ + gc] + be[gc];
#pragma unroll
    for (int mi = 0; mi < 4; ++mi)
#pragma unroll
      for (int j = 0; j < 4; ++j)
        uacc[mi][j] += vv * fast_tanh(base + acc[mi][ni][j]);
  }
#pragma unroll
  for (int mi = 0; mi < 4; ++mi)
#pragma unroll
    for (int j = 0; j < 4; ++j) {
      float s = uacc[mi][j];
      s += __shfl_xor(s, 1);
      s += __shfl_xor(s, 2);
      s += __shfl_xor(s, 4);
      s += __shfl_xor(s, 8);
      if (lr == 0) ured[w][mi * 16 + (lg << 2) + j] = s;
    }
  __syncthreads();
  if (t < 128) {
    const int r = t & 63, half = t >> 6;   // half 0: waves 0+1; 1: waves 2+3
    ui4[nt * (B_ * S_) + row0 + half * 64 + r] =
        ured[half * 2][r] + ured[half * 2 + 1][r];
  }
}

// ---------------------------------------------------------------------------
// softmax over S per batch row: sums the 4 ui partials, applies mask -> -inf.
__global__ void k_softmax(const float* __restrict__ ui4, const void* __restrict__ mask,
                          float* __restrict__ alpha) {
  __shared__ float red[4];
  __shared__ int sfl;
  const int b = blockIdx.x, t = threadIdx.x;
  const int l = t & 63, w = t >> 6;

  if (t == 0) sfl = 0;
  const unsigned int* mw = (const unsigned int*)mask;
  unsigned det = (mw[b * 512 + t] | mw[b * 512 + 256 + t]) & 0xFFFFFF00u;
  __syncthreads();
  if (det) atomicOr(&sfl, 1);
  __syncthreads();
  const int fl = sfl;   // 1 => byte layout

  float u[8];
#pragma unroll
  for (int i = 0; i < 8; ++i) {
    const int idx = b * S_ + t + i * 256;
    const int msk = fl ? (int)((const unsigned char*)mask)[idx]
                       : ((const int*)mask)[idx];
    const float uv = ui4[idx] + ui4[idx + B_ * S_] + ui4[idx + 2 * B_ * S_] +
                     ui4[idx + 3 * B_ * S_];
    u[i] = msk ? -__builtin_inff() : uv;
  }

  float mx = u[0];
#pragma unroll
  for (int i = 1; i < 8; ++i) mx = fmaxf(mx, u[i]);
#pragma unroll
  for (int off = 32; off; off >>= 1) mx = fmaxf(mx, __shfl_xor(mx, off));
  if (l == 0) red[w] = mx;
  __syncthreads();
  mx = fmaxf(fmaxf(red[0], red[1]), fmaxf(red[2], red[3]));
  __syncthreads();

  float p[8];
  float s = 0.f;
#pragma unroll
  for (int i = 0; i < 8; ++i) {
    p[i] = __builtin_amdgcn_exp2f((u[i] - mx) * 1.4426950408889634f);
    s += p[i];
  }
#pragma unroll
  for (int off = 32; off; off >>= 1) s += __shfl_xor(s, off);
  if (l == 0) red[w] = s;
  __syncthreads();
  s = red[0] + red[1] + red[2] + red[3];

  const float inv = 1.0f / s;
#pragma unroll
  for (int i = 0; i < 8; ++i) alpha[b * S_ + t + i * 256] = p[i] * inv;
}

// ---------------------------------------------------------------------------
// part[chunk][b][d] = sum over 128 s of alpha * ctx (fp32)
__global__ void k_wsum(const float* __restrict__ ctx, const float* __restrict__ alpha,
                       float* __restrict__ part) {
  __shared__ float red[3][512];
  const int b = blockIdx.x >> 4, chunk = blockIdx.x & 15;
  const int t = threadIdx.x;
  const int h0 = (t & 63) << 3;
  const int sw = t >> 6;
  const int s0 = chunk << 7;

  float acc[8] = {0.f, 0.f, 0.f, 0.f, 0.f, 0.f, 0.f, 0.f};
#pragma unroll 2
  for (int k = 0; k < 32; ++k) {
    const int s = s0 + sw + (k << 2);
    const float a = alpha[b * S_ + s];
    const f32x4* e = (const f32x4*)(ctx + ((size_t)(b * S_ + s)) * D_ + h0);
    f32x4 e0 = e[0], e1 = e[1];
#pragma unroll
    for (int j = 0; j < 4; ++j) acc[j] += a * e0[j];
#pragma unroll
    for (int j = 0; j < 4; ++j) acc[4 + j] += a * e1[j];
  }
  if (sw) {
#pragma unroll
    for (int j = 0; j < 8; ++j) red[sw - 1][h0 + j] = acc[j];
  }
  __syncthreads();
  if (sw == 0) {
#pragma unroll
    for (int j = 0; j < 8; ++j)
      part[((chunk << 6) + b) * 512 + h0 + j] =
          acc[j] + red[0][h0 + j] + red[1][h0 + j] + red[2][h0 + j];
  }
}

// ---------------------------------------------------------------------------
// k_tail: collapse part chunks into LDS wsum, then out1 = wsum.We^T + be
__global__ void k_tail(const float* __restrict__ part, const float* __restrict__ We,
                       const float* __restrict__ be, float* __restrict__ out1) {
  __shared__ float wsum_s[512];
  const int b = blockIdx.x, t = threadIdx.x;

  float s = 0.f;
#pragma unroll
  for (int c = 0; c < 16; ++c) s += part[((c << 6) + b) * 512 + t];
  wsum_s[t] = s;
  __syncthreads();

  const f32x4* wp = (const f32x4*)wsum_s;
  const f32x4* ep = (const f32x4*)(We + (size_t)t * D_);
  float acc = 0.f;
#pragma unroll 8
  for (int i = 0; i < D_ / 4; ++i) {
    f32x4 x = wp[i], y = ep[i];
    acc += x[0] * y[0] + x[1] * y[1] + x[2] * y[2] + x[3] * y[3];
  }
  out1[b * H_ + t] = acc + be[t];
}

// ---------------------------------------------------------------------------
extern "C" void kernel_launch(void* const* d_in, const int* in_sizes, int n_in,
                              void* d_out, int out_size, void* d_ws, size_t ws_size,
                              hipStream_t stream) {
  const float* hidden = (const float*)d_in[0];
  const float* ctx    = (const float*)d_in[1];
  const void*  mask   = d_in[2];
  const float* Wd     = (const float*)d_in[3];
  const float* bd     = (const float*)d_in[4];
  const float* We     = (const float*)d_in[5];
  const float* be     = (const float*)d_in[6];
  const float* V      = (const float*)d_in[7];

  float* out   = (float*)d_out;
  float* alpha = out;               // [B,S]
  float* out1  = out + B_ * S_;     // [B,H]

  // ws layout: ui4/part (2MB) | di (128KB) | Web (512KB)
  char* ws = (char*)d_ws;
  const size_t off_u2  = 0;
  const size_t off_r3  = off_u2 + 4ull * B_ * S_ * 4;   // +2 MiB
  const size_t off_web = off_r3 + (size_t)B_ * H_ * 4;  // +128 KiB

  float* ui4  = (float*)(ws + off_u2);
  float* part = (float*)(ws + off_u2);
  float* di   = (float*)(ws + off_r3);
  unsigned short* Web = (unsigned short*)(ws + off_web);

  k_prep<<<256, 256, 0, stream>>>(hidden, Wd, bd, di, We, Web);
  k_ei_gemm<<<(B_ * S_ / 128) * 4, 256, 0, stream>>>(ctx, Web, be, V, di, ui4);
  k_softmax<<<B_, 256, 0, stream>>>(ui4, mask, alpha);
  k_wsum<<<B_ * 16, 256, 0, stream>>>(ctx, alpha, part);
  k_tail<<<B_, 512, 0, stream>>>(part, We, be, out1);
}

// Round 10
// 205.399 us; speedup vs baseline: 3.4160x; 3.4160x over previous
//
#include <hip/hip_runtime.h>
#include <cstdint>

// Problem constants (B,S,D,H) from the reference
#define B_ 64
#define S_ 2048
#define D_ 512
#define H_ 512

using f32x4  = __attribute__((ext_vector_type(4))) float;
using bf16x8 = __attribute__((ext_vector_type(8))) short;

__device__ __forceinline__ unsigned short f2bf(float f) {
  unsigned u = __float_as_uint(f);
  u += 0x7FFFu + ((u >> 16) & 1u);   // round-to-nearest-even
  return (unsigned short)(u >> 16);
}
// packed f32x2 -> bf16x2 (RTE), hardware op (no builtin on gfx950)
__device__ __forceinline__ unsigned int cvtpk(float lo, float hi) {
  unsigned int r;
  asm("v_cvt_pk_bf16_f32 %0, %1, %2" : "=v"(r) : "v"(lo), "v"(hi));
  return r;
}
// 8 fp32 -> bf16x8 fragment (k-ascending order preserved)
__device__ __forceinline__ bf16x8 cvt8(f32x4 a, f32x4 b) {
  union { unsigned int u[4]; bf16x8 v; } r;
  r.u[0] = cvtpk(a[0], a[1]); r.u[1] = cvtpk(a[2], a[3]);
  r.u[2] = cvtpk(b[0], b[1]); r.u[3] = cvtpk(b[2], b[3]);
  return r.v;
}
// tanh via v_exp_f32: 1 - 2/(exp2(2x*log2e)+1); exact saturation at +-inf
__device__ __forceinline__ float fast_tanh(float x) {
  float t = __builtin_amdgcn_exp2f(x * 2.8853900817779268f);
  return 1.0f - 2.0f * __builtin_amdgcn_rcpf(t + 1.0f);
}

// async global->LDS DMA, 16B/lane; dest = wave-uniform base + lane*16 (linear)
__device__ __forceinline__ void gl_lds16g(const void* g, void* l) {
  __builtin_amdgcn_global_load_lds(
      (const __attribute__((address_space(1))) unsigned int*)g,
      (__attribute__((address_space(3))) unsigned int*)l, 16, 0, 0);
}

__device__ __forceinline__ void barrier_raw() {
  asm volatile("" ::: "memory");
  __builtin_amdgcn_s_barrier();
  asm volatile("" ::: "memory");
}

// ---------------------------------------------------------------------------
// k_prep: blocks [0,128): di[b,h] = hidden[b,:].Wd[h,:] + bd[h]
//         blocks [128,256): We fp32 -> bf16 (32768 chunks of 8)
__global__ void k_prep(const float* __restrict__ hidden, const float* __restrict__ Wd,
                       const float* __restrict__ bd, float* __restrict__ di,
                       const float* __restrict__ We, unsigned short* __restrict__ Web) {
  if (blockIdx.x < 128) {
    int idx = blockIdx.x * 256 + threadIdx.x;   // 32768 total
    int h = idx >> 6;
    int b = idx & 63;
    const f32x4* hp = (const f32x4*)(hidden + (size_t)b * D_);
    const f32x4* wp = (const f32x4*)(Wd + (size_t)h * D_);
    float acc = 0.f;
#pragma unroll 8
    for (int i = 0; i < D_ / 4; ++i) {
      f32x4 x = hp[i], y = wp[i];
      acc += x[0] * y[0] + x[1] * y[1] + x[2] * y[2] + x[3] * y[3];
    }
    di[b * H_ + h] = acc + bd[h];
  } else {
    int i = (blockIdx.x - 128) * 256 + threadIdx.x;   // 32768 chunks
    const f32x4* p = (const f32x4*)(We + (size_t)i * 8);
    f32x4 a = p[0], b = p[1];
    bf16x8 o;
    o[0] = (short)f2bf(a[0]); o[1] = (short)f2bf(a[1]);
    o[2] = (short)f2bf(a[2]); o[3] = (short)f2bf(a[3]);
    o[4] = (short)f2bf(b[0]); o[5] = (short)f2bf(b[1]);
    o[6] = (short)f2bf(b[2]); o[7] = (short)f2bf(b[3]);
    *(bf16x8*)(Web + (size_t)i * 8) = o;
  }
}

// ---------------------------------------------------------------------------
// ei-GEMM: tile 128x256 (nt=2 -> A L2-refetch halved), 8 waves (2M x 4N,
// 64x64 each), BK=32, 16 ksteps, 66 KB LDS, 2 blocks/CU.
// ALL staging via global_load_lds DMA (zero staging VGPRs, zero wave ds_writes):
//   A staged as RAW FP32 [128][32] (16 KB/buf), converted at fragment read
//   via v_cvt_pk_bf16_f32; B staged bf16 [256][32] (16 KB/buf).
// Schedule (m97 2-barrier + counted vmcnt):
//   prologue: STAGE(0,0); STAGE(1,1)          (4 gl_lds per wave per tile)
//   kstep kt: vmcnt(4)  // tile kt's 4 DMAs retired; kt+1's 4 stay in flight
//             barrier; ds_read frags (+cvt A); setprio(1) 16 MFMA setprio(0)
//             sched_barrier(0); barrier; STAGE(bf, kt+2)
// Swizzles (both-sides-or-neither, DMA dest linear -> source pre-swizzled):
//   A: 128B rows, 8 slots: phys = s ^ (row&7)   -> read slot (2lg+j)^(lr&7)
//   B: 64B rows, 4 slots: phys = s ^ ((row>>1)&3) -> read slot lg^((lr>>1)&3)
__global__ __launch_bounds__(512, 2) void k_ei_gemm(
    const float* __restrict__ A, const unsigned short* __restrict__ Bw,
    const float* __restrict__ be, const float* __restrict__ V,
    const float* __restrict__ di, float* __restrict__ ui2) {
  __shared__ __align__(16) float ldsA[2][128 * 32];            // 16 KB each
  __shared__ __align__(16) unsigned short ldsB[2][256 * 32];   // 16 KB each
  __shared__ float ured[8][64];

  const int bid = blockIdx.x;
  const int swz = (bid & 7) * 256 + (bid >> 3);   // bijective XCD chunking (2048%8==0)
  const int row0 = (swz >> 1) << 7;               // 1024 m-tiles of 128 rows
  const int nt   = swz & 1;
  const int cb   = nt << 8;                       // col base (0 or 256)

  const int t  = threadIdx.x;
  const int l  = t & 63;
  const int w  = t >> 6;          // 8 waves: 2M x 4N
  const int wm = (w >> 2) << 6;
  const int wn = (w & 3) << 6;
  const int lr = l & 15;
  const int lg = l >> 4;

  // DMA sources, slot-preswizzled (dest is linear: lane l -> row l>>3 (A) or
  // l>>2 (B), phys slot l&7 / l&3)
  const float* gA = A + (size_t)(row0 + w * 8 + (l >> 3)) * D_ +
                    (((l & 7) ^ ((l >> 3) & 7)) << 2);
  const unsigned short* gB = Bw + (size_t)(cb + w * 16 + (l >> 2)) * D_ +
                             (((l & 3) ^ ((l >> 3) & 3)) << 3);

#define STAGE(bf, kk) do {                                     \
    const int k0_ = (kk) << 5;                                 \
    gl_lds16g(gA + k0_,            &ldsA[bf][w * 256]);        \
    gl_lds16g(gA + 64 * D_ + k0_,  &ldsA[bf][2048 + w * 256]); \
    gl_lds16g(gB + k0_,            &ldsB[bf][w * 512]);        \
    gl_lds16g(gB + 128 * D_ + k0_, &ldsB[bf][4096 + w * 512]); \
  } while (0)

  // read-side offsets
  const int pa0 = (((2 * lg)     ^ (lr & 7)) << 2);   // fp32 elems
  const int pa1 = (((2 * lg + 1) ^ (lr & 7)) << 2);
  const int rsB = (lg ^ ((lr >> 1) & 3)) << 3;        // bf16 elems
  const int arow = (wm + lr) * 32;                    // + mi*512
  const int brow = (wn + lr) * 32;                    // + ni*512

  f32x4 acc[4][4];
  const f32x4 z = {0.f, 0.f, 0.f, 0.f};
#pragma unroll
  for (int mi = 0; mi < 4; ++mi)
#pragma unroll
    for (int ni = 0; ni < 4; ++ni) acc[mi][ni] = z;

  STAGE(0, 0);
  STAGE(1, 1);

#pragma unroll
  for (int kt = 0; kt < 16; ++kt) {
    if (kt == 15) asm volatile("s_waitcnt vmcnt(0)" ::: "memory");
    else          asm volatile("s_waitcnt vmcnt(4)" ::: "memory");
    barrier_raw();                       // tile kt resident block-wide
    const int bf = kt & 1;

    bf16x8 bq0 = *(const bf16x8*)&ldsB[bf][brow + 0 * 512 + rsB];
    bf16x8 bq1 = *(const bf16x8*)&ldsB[bf][brow + 1 * 512 + rsB];
    bf16x8 bq2 = *(const bf16x8*)&ldsB[bf][brow + 2 * 512 + rsB];
    bf16x8 bq3 = *(const bf16x8*)&ldsB[bf][brow + 3 * 512 + rsB];

    __builtin_amdgcn_s_setprio(1);
    // half 0: mi = 0,1 (raw fp32 -> cvt -> MFMA)
    {
      f32x4 r00 = *(const f32x4*)&ldsA[bf][arow + 0 * 512 + pa0];
      f32x4 r01 = *(const f32x4*)&ldsA[bf][arow + 0 * 512 + pa1];
      f32x4 r10 = *(const f32x4*)&ldsA[bf][arow + 1 * 512 + pa0];
      f32x4 r11 = *(const f32x4*)&ldsA[bf][arow + 1 * 512 + pa1];
      bf16x8 af0 = cvt8(r00, r01);
      bf16x8 af1 = cvt8(r10, r11);
      acc[0][0] = __builtin_amdgcn_mfma_f32_16x16x32_bf16(af0, bq0, acc[0][0], 0, 0, 0);
      acc[0][1] = __builtin_amdgcn_mfma_f32_16x16x32_bf16(af0, bq1, acc[0][1], 0, 0, 0);
      acc[0][2] = __builtin_amdgcn_mfma_f32_16x16x32_bf16(af0, bq2, acc[0][2], 0, 0, 0);
      acc[0][3] = __builtin_amdgcn_mfma_f32_16x16x32_bf16(af0, bq3, acc[0][3], 0, 0, 0);
      acc[1][0] = __builtin_amdgcn_mfma_f32_16x16x32_bf16(af1, bq0, acc[1][0], 0, 0, 0);
      acc[1][1] = __builtin_amdgcn_mfma_f32_16x16x32_bf16(af1, bq1, acc[1][1], 0, 0, 0);
      acc[1][2] = __builtin_amdgcn_mfma_f32_16x16x32_bf16(af1, bq2, acc[1][2], 0, 0, 0);
      acc[1][3] = __builtin_amdgcn_mfma_f32_16x16x32_bf16(af1, bq3, acc[1][3], 0, 0, 0);
    }
    // half 1: mi = 2,3
    {
      f32x4 r20 = *(const f32x4*)&ldsA[bf][arow + 2 * 512 + pa0];
      f32x4 r21 = *(const f32x4*)&ldsA[bf][arow + 2 * 512 + pa1];
      f32x4 r30 = *(const f32x4*)&ldsA[bf][arow + 3 * 512 + pa0];
      f32x4 r31 = *(const f32x4*)&ldsA[bf][arow + 3 * 512 + pa1];
      bf16x8 af2 = cvt8(r20, r21);
      bf16x8 af3 = cvt8(r30, r31);
      acc[2][0] = __builtin_amdgcn_mfma_f32_16x16x32_bf16(af2, bq0, acc[2][0], 0, 0, 0);
      acc[2][1] = __builtin_amdgcn_mfma_f32_16x16x32_bf16(af2, bq1, acc[2][1], 0, 0, 0);
      acc[2][2] = __builtin_amdgcn_mfma_f32_16x16x32_bf16(af2, bq2, acc[2][2], 0, 0, 0);
      acc[2][3] = __builtin_amdgcn_mfma_f32_16x16x32_bf16(af2, bq3, acc[2][3], 0, 0, 0);
      acc[3][0] = __builtin_amdgcn_mfma_f32_16x16x32_bf16(af3, bq0, acc[3][0], 0, 0, 0);
      acc[3][1] = __builtin_amdgcn_mfma_f32_16x16x32_bf16(af3, bq1, acc[3][1], 0, 0, 0);
      acc[3][2] = __builtin_amdgcn_mfma_f32_16x16x32_bf16(af3, bq2, acc[3][2], 0, 0, 0);
      acc[3][3] = __builtin_amdgcn_mfma_f32_16x16x32_bf16(af3, bq3, acc[3][3], 0, 0, 0);
    }
    __builtin_amdgcn_s_setprio(0);

    __builtin_amdgcn_sched_barrier(0);   // pin reads/MFMA above barrier-2
    barrier_raw();                       // all reads of buf[bf] retired
    if (kt + 2 < 16) STAGE(bf, kt + 2);  // DMA overwrite now safe
  }
#undef STAGE

  // fused ui partials over this block's 256 columns; atomic-free.
  // C/D layout: col = lr, row = lg*4 + j within each 16x16 frag.
  const int b = row0 >> 11;   // BM=128 divides S=2048 -> block-uniform batch
  float uacc[4][4];
#pragma unroll
  for (int mi = 0; mi < 4; ++mi)
#pragma unroll
    for (int j = 0; j < 4; ++j) uacc[mi][j] = 0.f;

#pragma unroll
  for (int ni = 0; ni < 4; ++ni) {
    const int gc = cb + wn + ni * 16 + lr;
    const float vv = V[gc];
    const float base = di[b * H_ + gc] + be[gc];
#pragma unroll
    for (int mi = 0; mi < 4; ++mi)
#pragma unroll
      for (int j = 0; j < 4; ++j)
        uacc[mi][j] += vv * fast_tanh(base + acc[mi][ni][j]);
  }
  // reduce across the 16 lr-lanes; lanes lr==0 (lg=0..3) hold 4-row sums
#pragma unroll
  for (int mi = 0; mi < 4; ++mi)
#pragma unroll
    for (int j = 0; j < 4; ++j) {
      float s = uacc[mi][j];
      s += __shfl_xor(s, 1);
      s += __shfl_xor(s, 2);
      s += __shfl_xor(s, 4);
      s += __shfl_xor(s, 8);
      if (lr == 0) ured[w][mi * 16 + (lg << 2) + j] = s;
    }
  __syncthreads();
  if (t < 128) {
    const int r = t & 63, wr = t >> 6;   // waves wr*4 .. wr*4+3 share rows
    ui2[nt * (B_ * S_) + row0 + wr * 64 + r] =
        ured[wr * 4][r] + ured[wr * 4 + 1][r] + ured[wr * 4 + 2][r] +
        ured[wr * 4 + 3][r];
  }
}

// ---------------------------------------------------------------------------
// softmax over S per batch row: sums the 2 ui partials, applies mask -> -inf.
// Mask dtype (bool-bytes vs int32) detected per block from word high-bytes
// (scan limited to first 128KB so it is in-bounds under both layouts).
__global__ void k_softmax(const float* __restrict__ ui2, const void* __restrict__ mask,
                          float* __restrict__ alpha) {
  __shared__ float red[4];
  __shared__ int sfl;
  const int b = blockIdx.x, t = threadIdx.x;
  const int l = t & 63, w = t >> 6;

  if (t == 0) sfl = 0;
  const unsigned int* mw = (const unsigned int*)mask;
  unsigned det = (mw[b * 512 + t] | mw[b * 512 + 256 + t]) & 0xFFFFFF00u;
  __syncthreads();
  if (det) atomicOr(&sfl, 1);
  __syncthreads();
  const int fl = sfl;   // 1 => byte layout

  float u[8];
#pragma unroll
  for (int i = 0; i < 8; ++i) {
    const int idx = b * S_ + t + i * 256;
    const int msk = fl ? (int)((const unsigned char*)mask)[idx]
                       : ((const int*)mask)[idx];
    const float uv = ui2[idx] + ui2[idx + B_ * S_];
    u[i] = msk ? -__builtin_inff() : uv;
  }

  float mx = u[0];
#pragma unroll
  for (int i = 1; i < 8; ++i) mx = fmaxf(mx, u[i]);
#pragma unroll
  for (int off = 32; off; off >>= 1) mx = fmaxf(mx, __shfl_xor(mx, off));
  if (l == 0) red[w] = mx;
  __syncthreads();
  mx = fmaxf(fmaxf(red[0], red[1]), fmaxf(red[2], red[3]));
  __syncthreads();

  float p[8];
  float s = 0.f;
#pragma unroll
  for (int i = 0; i < 8; ++i) {
    p[i] = __builtin_amdgcn_exp2f((u[i] - mx) * 1.4426950408889634f);
    s += p[i];
  }
#pragma unroll
  for (int off = 32; off; off >>= 1) s += __shfl_xor(s, off);
  if (l == 0) red[w] = s;
  __syncthreads();
  s = red[0] + red[1] + red[2] + red[3];

  const float inv = 1.0f / s;
#pragma unroll
  for (int i = 0; i < 8; ++i) alpha[b * S_ + t + i * 256] = p[i] * inv;
}

// ---------------------------------------------------------------------------
// part[chunk][b][d] = sum over 128 s of alpha * ctx (fp32)
__global__ void k_wsum(const float* __restrict__ ctx, const float* __restrict__ alpha,
                       float* __restrict__ part) {
  __shared__ float red[3][512];
  const int b = blockIdx.x >> 4, chunk = blockIdx.x & 15;
  const int t = threadIdx.x;
  const int h0 = (t & 63) << 3;
  const int sw = t >> 6;
  const int s0 = chunk << 7;

  float acc[8] = {0.f, 0.f, 0.f, 0.f, 0.f, 0.f, 0.f, 0.f};
#pragma unroll 2
  for (int k = 0; k < 32; ++k) {
    const int s = s0 + sw + (k << 2);
    const float a = alpha[b * S_ + s];
    const f32x4* e = (const f32x4*)(ctx + ((size_t)(b * S_ + s)) * D_ + h0);
    f32x4 e0 = e[0], e1 = e[1];
#pragma unroll
    for (int j = 0; j < 4; ++j) acc[j] += a * e0[j];
#pragma unroll
    for (int j = 0; j < 4; ++j) acc[4 + j] += a * e1[j];
  }
  if (sw) {
#pragma unroll
    for (int j = 0; j < 8; ++j) red[sw - 1][h0 + j] = acc[j];
  }
  __syncthreads();
  if (sw == 0) {
#pragma unroll
    for (int j = 0; j < 8; ++j)
      part[((chunk << 6) + b) * 512 + h0 + j] =
          acc[j] + red[0][h0 + j] + red[1][h0 + j] + red[2][h0 + j];
  }
}

// ---------------------------------------------------------------------------
// k_tail: collapse part chunks into LDS wsum, then out1 = wsum.We^T + be
__global__ void k_tail(const float* __restrict__ part, const float* __restrict__ We,
                       const float* __restrict__ be, float* __restrict__ out1) {
  __shared__ float wsum_s[512];
  const int b = blockIdx.x, t = threadIdx.x;

  float s = 0.f;
#pragma unroll
  for (int c = 0; c < 16; ++c) s += part[((c << 6) + b) * 512 + t];
  wsum_s[t] = s;
  __syncthreads();

  const f32x4* wp = (const f32x4*)wsum_s;
  const f32x4* ep = (const f32x4*)(We + (size_t)t * D_);
  float acc = 0.f;
#pragma unroll 8
  for (int i = 0; i < D_ / 4; ++i) {
    f32x4 x = wp[i], y = ep[i];
    acc += x[0] * y[0] + x[1] * y[1] + x[2] * y[2] + x[3] * y[3];
  }
  out1[b * H_ + t] = acc + be[t];
}

// ---------------------------------------------------------------------------
extern "C" void kernel_launch(void* const* d_in, const int* in_sizes, int n_in,
                              void* d_out, int out_size, void* d_ws, size_t ws_size,
                              hipStream_t stream) {
  const float* hidden = (const float*)d_in[0];
  const float* ctx    = (const float*)d_in[1];
  const void*  mask   = d_in[2];
  const float* Wd     = (const float*)d_in[3];
  const float* bd     = (const float*)d_in[4];
  const float* We     = (const float*)d_in[5];
  const float* be     = (const float*)d_in[6];
  const float* V      = (const float*)d_in[7];

  float* out   = (float*)d_out;
  float* alpha = out;               // [B,S]
  float* out1  = out + B_ * S_;     // [B,H]

  // ws layout: ui2/part (2MB region) | di (128KB) | Web (512KB)
  char* ws = (char*)d_ws;
  const size_t off_u2  = 0;
  const size_t off_r3  = off_u2 + 4ull * B_ * S_ * 4;   // +2 MiB
  const size_t off_web = off_r3 + (size_t)B_ * H_ * 4;  // +128 KiB

  float* ui2  = (float*)(ws + off_u2);
  float* part = (float*)(ws + off_u2);
  float* di   = (float*)(ws + off_r3);
  unsigned short* Web = (unsigned short*)(ws + off_web);

  k_prep<<<256, 256, 0, stream>>>(hidden, Wd, bd, di, We, Web);
  k_ei_gemm<<<(B_ * S_ / 128) * 2, 512, 0, stream>>>(ctx, Web, be, V, di, ui2);
  k_softmax<<<B_, 256, 0, stream>>>(ui2, mask, alpha);
  k_wsum<<<B_ * 16, 256, 0, stream>>>(ctx, alpha, part);
  k_tail<<<B_, 512, 0, stream>>>(part, We, be, out1);
}